// Round 8
// baseline (231.423 us; speedup 1.0000x reference)
//
#include <hip/hip_runtime.h>

typedef __bf16 bf16;
typedef __attribute__((ext_vector_type(4))) __bf16 bf16x4;
typedef __attribute__((ext_vector_type(8))) __bf16 bf16x8;
typedef __attribute__((ext_vector_type(4))) float f32x4;

#define B_   4
#define T_   2048
#define C_   768
#define H_   8
#define HS_  96
#define M_   (B_ * T_)      /* 8192 */
#define QKN_ (3 * C_)       /* 2304 */

#define NEG_BIG (-1e30f)

// LDS strides (elements) for attn tiles
#define KSTR 104   /* 64x(96) K tile rows, padded 96->104 */
#define VSTR 72    /* 96x(64) Vt tile rows, padded 64->72 */

// ---------------------------------------------------------------------------
// async global->LDS, 16B per lane. LDS dest must be wave-uniform base;
// HW writes base + lane*16 (m104). Global addr is per-lane.
// ---------------------------------------------------------------------------
__device__ __forceinline__ void gload_lds16(const bf16* g, bf16* l) {
    __builtin_amdgcn_global_load_lds(
        (const __attribute__((address_space(1))) uint32_t*)g,
        (__attribute__((address_space(3))) uint32_t*)l,
        16, 0, 0);
}

__device__ __forceinline__ bf16x8 cvt8(f32x4 v0, f32x4 v1) {
    bf16x8 o;
#pragma unroll
    for (int i = 0; i < 4; ++i) { o[i] = (bf16)v0[i]; o[4 + i] = (bf16)v1[i]; }
    return o;
}

// ---------------------------------------------------------------------------
// Transpose + convert: W[R][Cn] (fp32) -> Wt[Cn][R] (bf16)  (path-B fallback)
// ---------------------------------------------------------------------------
__global__ void transpose_kernel(const float* __restrict__ W, bf16* __restrict__ Wt,
                                 int R, int Cn) {
    __shared__ bf16 tile[32][33];
    int tx = threadIdx.x, ty = threadIdx.y;
    int x  = blockIdx.x * 32 + tx;
    int y0 = blockIdx.y * 32;
#pragma unroll
    for (int j = 0; j < 32; j += 8)
        tile[ty + j][tx] = (bf16)W[(size_t)(y0 + ty + j) * Cn + x];
    __syncthreads();
    int y2 = blockIdx.x * 32;
    int x2 = y0 + tx;
#pragma unroll
    for (int j = 0; j < 32; j += 8)
        Wt[(size_t)(y2 + ty + j) * R + x2] = tile[tx][ty + j];
}

// ---------------------------------------------------------------------------
__global__ void sentinel_kernel(float* __restrict__ out, int n) {
    int i = blockIdx.x * 256 + threadIdx.x;
    if (i < n) out[i] = 12345.0f;
}

// ---------------------------------------------------------------------------
// One-shot fp32 -> bf16 convert (x -> xb)  (path-B fallback)
// ---------------------------------------------------------------------------
__global__ __launch_bounds__(256) void convert_bf16_kernel(const float* __restrict__ in,
                                                           bf16* __restrict__ out,
                                                           int n8) {
    int i = blockIdx.x * 256 + threadIdx.x;
    if (i >= n8) return;
    const float* p = in + (size_t)i * 8;
    f32x4 a = *(const f32x4*)p;
    f32x4 b = *(const f32x4*)(p + 4);
    *(bf16x8*)&out[(size_t)i * 8] = cvt8(a, b);
}

// ---------------------------------------------------------------------------
// Merged prep: convert x->xb (bf16) + transpose both weights, one launch.
// ---------------------------------------------------------------------------
#define CONV_BLKS (M_ * C_ / 8 / 256)          /* 3072 */
#define TA_BX (QKN_ / 32)                      /* 72 */
#define TA_BLKS (TA_BX * (C_ / 32))            /* 1728 */
#define TP_BX (C_ / 32)                        /* 24 */
#define TP_BLKS (TP_BX * (C_ / 32))            /* 576 */

__device__ __forceinline__ void transpose_body(bf16 (*tile)[33],
                                               const float* __restrict__ W,
                                               bf16* __restrict__ Wt,
                                               int R, int Cn, int bx, int by, int tid) {
    int tx = tid & 31, ty = tid >> 5;
    int x  = bx * 32 + tx;
    int y0 = by * 32;
#pragma unroll
    for (int j = 0; j < 32; j += 8)
        tile[ty + j][tx] = (bf16)W[(size_t)(y0 + ty + j) * Cn + x];
    __syncthreads();
    int y2 = bx * 32;
    int x2 = y0 + tx;
#pragma unroll
    for (int j = 0; j < 32; j += 8)
        Wt[(size_t)(y2 + ty + j) * R + x2] = tile[tx][ty + j];
}

__global__ __launch_bounds__(256) void prep_kernel(const float* __restrict__ x,
                                                   bf16* __restrict__ xb,
                                                   const float* __restrict__ Wa,
                                                   bf16* __restrict__ Wta,
                                                   const float* __restrict__ Wp,
                                                   bf16* __restrict__ Wtp) {
    __shared__ bf16 tile[32][33];
    int bid = blockIdx.x;
    int tid = threadIdx.x;
    if (bid < CONV_BLKS) {
        int i = bid * 256 + tid;
        const float* p = x + (size_t)i * 8;
        f32x4 a = *(const f32x4*)p;
        f32x4 b = *(const f32x4*)(p + 4);
        *(bf16x8*)&xb[(size_t)i * 8] = cvt8(a, b);
    } else if (bid < CONV_BLKS + TA_BLKS) {
        int t = bid - CONV_BLKS;
        transpose_body(tile, Wa, Wta, C_, QKN_, t % TA_BX, t / TA_BX, tid);
    } else {
        int t = bid - CONV_BLKS - TA_BLKS;
        transpose_body(tile, Wp, Wtp, C_, C_, t % TP_BX, t / TP_BX, tid);
    }
}

#define TILE_ELEMS (128 * 64)

// ---------------------------------------------------------------------------
// GEMM1 (T3 minimum 2-phase): qkv[M][2304] = xb[M][768](bf16) @ Bt^T + b.
// Vt epilogue k-permutes t within each 64-tile:
//   p(k) = (k&3) + (((k>>2)&7)<<3) + ((k>>5)<<2)
// so attn's permuted-k PV reads V as contiguous b128 (conflict-free).
// ---------------------------------------------------------------------------
__global__ __launch_bounds__(256) void gemm_qkv(const bf16* __restrict__ A,
                                                const bf16* __restrict__ Bt,
                                                const float* __restrict__ bias,
                                                bf16* __restrict__ Cmat,
                                                bf16* __restrict__ Vt,
                                                int M, int N, int K) {
    __shared__ bf16 lda[2 * TILE_ELEMS];
    __shared__ bf16 ldb[2 * TILE_ELEMS];
    int tid  = threadIdx.x;
    int w    = tid >> 6;
    int lane = tid & 63;
    int col  = lane & 15, quad = lane >> 4;
    int wr   = w >> 1, wc = w & 1;
    int m0   = blockIdx.y * 128, n0 = blockIdx.x * 128;

    int srow = lane >> 3;
    int scol = (lane & 7) * 8;
    const bf16* gA[4]; const bf16* gB[4]; bf16* lA[4]; bf16* lB[4];
#pragma unroll
    for (int i = 0; i < 4; ++i) {
        int seg = w * 4 + i;
        int row = seg * 8 + srow;
        gA[i] = &A[(size_t)(m0 + row) * K + scol];
        gB[i] = &Bt[(size_t)(n0 + row) * K + scol];
        lA[i] = &lda[seg * 512];
        lB[i] = &ldb[seg * 512];
    }

    const f32x4 zero = {0.f, 0.f, 0.f, 0.f};
    f32x4 acc[4][4];
#pragma unroll
    for (int mr = 0; mr < 4; ++mr)
#pragma unroll
        for (int nc = 0; nc < 4; ++nc) acc[mr][nc] = zero;

#pragma unroll
    for (int i = 0; i < 4; ++i) {
        gload_lds16(gA[i], lA[i]);
        gload_lds16(gB[i], lB[i]);
    }
    __syncthreads();

    int cur = 0;
    for (int k0 = 0; k0 < K; k0 += 64) {
        int nxt = cur ^ 1;
        if (k0 + 64 < K) {
#pragma unroll
            for (int i = 0; i < 4; ++i) {
                gload_lds16(gA[i] + k0 + 64, lA[i] + nxt * TILE_ELEMS);
                gload_lds16(gB[i] + k0 + 64, lB[i] + nxt * TILE_ELEMS);
            }
        }
        const bf16* la = &lda[cur * TILE_ELEMS];
        const bf16* lb = &ldb[cur * TILE_ELEMS];
#pragma unroll
        for (int ks = 0; ks < 2; ++ks) {
            bf16x8 af[4], bfr[4];
#pragma unroll
            for (int t = 0; t < 4; ++t) {
                af[t]  = *(const bf16x8*)&la[(wr * 64 + t * 16 + col) * 64 + ks * 32 + quad * 8];
                bfr[t] = *(const bf16x8*)&lb[(wc * 64 + t * 16 + col) * 64 + ks * 32 + quad * 8];
            }
#pragma unroll
            for (int mr = 0; mr < 4; ++mr)
#pragma unroll
                for (int nc = 0; nc < 4; ++nc)
                    acc[mr][nc] = __builtin_amdgcn_mfma_f32_16x16x32_bf16(
                        af[mr], bfr[nc], acc[mr][nc], 0, 0, 0);
        }
        __syncthreads();
        cur = nxt;
    }

#pragma unroll
    for (int nc = 0; nc < 4; ++nc) {
        int n = n0 + wc * 64 + nc * 16 + col;
        float bv = bias[n];
#pragma unroll
        for (int mr = 0; mr < 4; ++mr) {
#pragma unroll
            for (int r = 0; r < 4; ++r) {
                int row = m0 + wr * 64 + mr * 16 + quad * 4 + r;
                Cmat[(size_t)row * N + n] = (bf16)(acc[mr][nc][r] + bv);
            }
        }
    }
    if (n0 >= 2 * C_) {
        int batch = m0 >> 11;
        bf16* Vtb = Vt + (size_t)batch * C_ * T_;
        int t0 = (m0 & 2047) + wr * 64;
#pragma unroll
        for (int nc = 0; nc < 4; ++nc) {
            int n  = n0 + wc * 64 + nc * 16 + col;
            int vc = n - 2 * C_;
            float bv = bias[n];
#pragma unroll
            for (int mr = 0; mr < 4; ++mr) {
                int t  = t0 + mr * 16 + quad * 4;
                int tb = t & ~63;                 // 64-tile base
                int a  = (t >> 2) & 15;           // 4-chunk index in tile
                int ts = tb + ((a & 7) << 3) + ((a >> 3) << 2);  // permuted base
                bf16x4 pk = {(bf16)(acc[mr][nc][0] + bv), (bf16)(acc[mr][nc][1] + bv),
                             (bf16)(acc[mr][nc][2] + bv), (bf16)(acc[mr][nc][3] + bv)};
                *(bf16x4*)&Vtb[(size_t)vc * T_ + ts] = pk;
            }
        }
    }
}

// ---------------------------------------------------------------------------
// GEMM2 (T3 minimum 2-phase): out[M][768](fp32) = yb[M][768](bf16) @ Bt^T + b.
// ---------------------------------------------------------------------------
__global__ __launch_bounds__(256) void gemm_proj(const bf16* __restrict__ A,
                                                 const bf16* __restrict__ Bt,
                                                 const float* __restrict__ bias,
                                                 float* __restrict__ Cmat,
                                                 int M, int N, int K) {
    __shared__ bf16 lda[2 * TILE_ELEMS];
    __shared__ bf16 ldb[2 * TILE_ELEMS];
    int tid  = threadIdx.x;
    int w    = tid >> 6;
    int lane = tid & 63;
    int col  = lane & 15, quad = lane >> 4;
    int wr   = w >> 1, wc = w & 1;
    int m0   = blockIdx.y * 128, n0 = blockIdx.x * 128;

    int srow = lane >> 3;
    int scol = (lane & 7) * 8;
    const bf16* gA[4]; const bf16* gB[4]; bf16* lA[4]; bf16* lB[4];
#pragma unroll
    for (int i = 0; i < 4; ++i) {
        int seg = w * 4 + i;
        int row = seg * 8 + srow;
        gA[i] = &A[(size_t)(m0 + row) * K + scol];
        gB[i] = &Bt[(size_t)(n0 + row) * K + scol];
        lA[i] = &lda[seg * 512];
        lB[i] = &ldb[seg * 512];
    }

    const f32x4 zero = {0.f, 0.f, 0.f, 0.f};
    f32x4 acc[4][4];
#pragma unroll
    for (int mr = 0; mr < 4; ++mr)
#pragma unroll
        for (int nc = 0; nc < 4; ++nc) acc[mr][nc] = zero;

#pragma unroll
    for (int i = 0; i < 4; ++i) {
        gload_lds16(gA[i], lA[i]);
        gload_lds16(gB[i], lB[i]);
    }
    __syncthreads();

    int cur = 0;
    for (int k0 = 0; k0 < K; k0 += 64) {
        int nxt = cur ^ 1;
        if (k0 + 64 < K) {
#pragma unroll
            for (int i = 0; i < 4; ++i) {
                gload_lds16(gA[i] + k0 + 64, lA[i] + nxt * TILE_ELEMS);
                gload_lds16(gB[i] + k0 + 64, lB[i] + nxt * TILE_ELEMS);
            }
        }
        const bf16* la = &lda[cur * TILE_ELEMS];
        const bf16* lb = &ldb[cur * TILE_ELEMS];
#pragma unroll
        for (int ks = 0; ks < 2; ++ks) {
            bf16x8 af[4], bfr[4];
#pragma unroll
            for (int t = 0; t < 4; ++t) {
                af[t]  = *(const bf16x8*)&la[(wr * 64 + t * 16 + col) * 64 + ks * 32 + quad * 8];
                bfr[t] = *(const bf16x8*)&lb[(wc * 64 + t * 16 + col) * 64 + ks * 32 + quad * 8];
            }
#pragma unroll
            for (int mr = 0; mr < 4; ++mr)
#pragma unroll
                for (int nc = 0; nc < 4; ++nc)
                    acc[mr][nc] = __builtin_amdgcn_mfma_f32_16x16x32_bf16(
                        af[mr], bfr[nc], acc[mr][nc], 0, 0, 0);
        }
        __syncthreads();
        cur = nxt;
    }

#pragma unroll
    for (int nc = 0; nc < 4; ++nc) {
        int n = n0 + wc * 64 + nc * 16 + col;
        float bv = bias[n];
#pragma unroll
        for (int mr = 0; mr < 4; ++mr) {
#pragma unroll
            for (int r = 0; r < 4; ++r) {
                int row = m0 + wr * 64 + mr * 16 + quad * 4 + r;
                Cmat[(size_t)row * N + n] = acc[mr][nc][r] + bv;
            }
        }
    }
}

// ---------------------------------------------------------------------------
// Fused causal flash attention — 128-ROW Q-BLOCKS, two q-groups per wave.
// Each wave owns rows w*16 (group A) and 64+w*16 (group B) of a 128-row
// q-tile; every K/V LDS b128 read now feeds TWO MFMAs (was one), halving
// LDS-reads/MFMA and barriers/MFMA. Group A skips the final tile
// (jt <= 2*qtt active; diagonal mask at jt==2*qtt); B masks at njt-1.
// Heavy-first (balanced-table reverted: r6 falsified CU-periodic dispatch).
// Static-exponent softmax, T14 prefetch, P-in-register permuted-k PV,
// k-permuted V store. No launch_bounds min-waves clamp (r3 spill lesson).
// (Resubmitted unchanged after r7 infra failure — audited: no hang/OOB.)
// ---------------------------------------------------------------------------
__global__ __launch_bounds__(256) void attn_kernel(const bf16* __restrict__ qkv,
                                                   const bf16* __restrict__ Vt,
                                                   bf16* __restrict__ y,
                                                   int nGroups) {
    __shared__ bf16 ldsK[64 * KSTR];
    __shared__ bf16 ldsV[96 * VSTR];
    const int bid  = blockIdx.x;
    const int qtt  = 15 - bid / nGroups;      // heavy 128-row tiles first
    const int g    = bid % nGroups;
    const int h    = g & 7, b = g >> 3;
    const int tid  = threadIdx.x;
    const int w    = tid >> 6, lane = tid & 63;
    const int col  = lane & 15, quad = lane >> 4;
    const float SCALE2 = 0.10206207261596577f * 1.4426950408889634f; // scale*log2e
    const float M0 = 24.0f;                    // static exponent shift (exact)
    const f32x4 zero = {0.f, 0.f, 0.f, 0.f};

    const bf16* qkvb = qkv + (size_t)b * T_ * QKN_;
    const bf16* Vtbh = Vt + (size_t)(b * H_ + h) * HS_ * T_;
    bf16* yb  = y + (size_t)b * T_ * C_;

    const int rbaseA = qtt * 128 + w * 16;
    const int rbaseB = rbaseA + 64;

    bf16x8 qfA[3], qfB[3];
#pragma unroll
    for (int c = 0; c < 3; ++c) {
        qfA[c] = *(const bf16x8*)&qkvb[(size_t)(rbaseA + col) * QKN_ + h * HS_ + c * 32 + quad * 8];
        qfB[c] = *(const bf16x8*)&qkvb[(size_t)(rbaseB + col) * QKN_ + h * HS_ + c * 32 + quad * 8];
    }

    const bf16* pK[3]; const bf16* pV[3];
    bf16 *dK[3], *dV[3];
#pragma unroll
    for (int i = 0; i < 3; ++i) {
        int chunk = i * 256 + tid;
        int rK = chunk / 12, cK = chunk - rK * 12;
        pK[i] = qkvb + (size_t)rK * QKN_ + C_ + h * HS_ + cK * 8;
        dK[i] = &ldsK[rK * KSTR + cK * 8];
        int rV = chunk >> 3, cV = chunk & 7;
        pV[i] = Vtbh + (size_t)rV * T_ + cV * 8;
        dV[i] = &ldsV[rV * VSTR + cV * 8];
    }

    f32x4 oA[6], oB[6];
#pragma unroll
    for (int n2 = 0; n2 < 6; ++n2) { oA[n2] = zero; oB[n2] = zero; }
    f32x4 lsumA4 = zero, lsumB4 = zero;

    // prologue: prefetch jt=0 K/V into registers
    bf16x8 kreg[3], vreg[3];
#pragma unroll
    for (int i = 0; i < 3; ++i) {
        kreg[i] = *(const bf16x8*)pK[i];
        vreg[i] = *(const bf16x8*)pV[i];
        pK[i] += (size_t)64 * QKN_;
        pV[i] += 64;
    }

    const int njt = 2 * qtt + 2;
    for (int jt = 0; jt < njt; ++jt) {
        const bool aAct = (jt <= 2 * qtt);
        int jb = jt * 64;
        __syncthreads();
        // write-late: regs -> LDS
#pragma unroll
        for (int i = 0; i < 3; ++i) {
            *(bf16x8*)dK[i] = kreg[i];
            *(bf16x8*)dV[i] = vreg[i];
        }
        __syncthreads();
        // issue-early: next tile's global loads fly under compute below
        if (jt + 1 < njt) {
#pragma unroll
            for (int i = 0; i < 3; ++i) {
                kreg[i] = *(const bf16x8*)pK[i];
                vreg[i] = *(const bf16x8*)pV[i];
                pK[i] += (size_t)64 * QKN_;
                pV[i] += 64;
            }
        }

        // QK^T: each kf read feeds BOTH q-groups
        f32x4 stA[4], stB[4];
#pragma unroll
        for (int nb = 0; nb < 4; ++nb) {
            stA[nb] = zero; stB[nb] = zero;
#pragma unroll
            for (int c = 0; c < 3; ++c) {
                bf16x8 kf = *(const bf16x8*)&ldsK[(nb * 16 + col) * KSTR + c * 32 + quad * 8];
                if (aAct)
                    stA[nb] = __builtin_amdgcn_mfma_f32_16x16x32_bf16(
                        kf, qfA[c], stA[nb], 0, 0, 0);
                stB[nb] = __builtin_amdgcn_mfma_f32_16x16x32_bf16(
                    kf, qfB[c], stB[nb], 0, 0, 0);
            }
        }

        // softmax A
        bf16x8 paloA, pahiA, paloB, pahiB;
        if (aAct) {
            if (jt == 2 * qtt) {
#pragma unroll
                for (int nb = 0; nb < 4; ++nb)
#pragma unroll
                    for (int r = 0; r < 4; ++r) {
                        int jg = jb + nb * 16 + quad * 4 + r;
                        stA[nb][r] = (jg <= rbaseA + col) ? fmaf(stA[nb][r], SCALE2, -M0)
                                                          : NEG_BIG;
                    }
            } else {
#pragma unroll
                for (int nb = 0; nb < 4; ++nb)
#pragma unroll
                    for (int r = 0; r < 4; ++r)
                        stA[nb][r] = fmaf(stA[nb][r], SCALE2, -M0);
            }
#pragma unroll
            for (int nb = 0; nb < 4; ++nb) {
#pragma unroll
                for (int r = 0; r < 4; ++r)
                    stA[nb][r] = exp2f(stA[nb][r]);
                lsumA4 += stA[nb];
            }
#pragma unroll
            for (int r = 0; r < 4; ++r) {
                paloA[r]     = (bf16)stA[0][r];
                paloA[4 + r] = (bf16)stA[2][r];
                pahiA[r]     = (bf16)stA[1][r];
                pahiA[4 + r] = (bf16)stA[3][r];
            }
        }
        // softmax B
        if (jt == njt - 1) {
#pragma unroll
            for (int nb = 0; nb < 4; ++nb)
#pragma unroll
                for (int r = 0; r < 4; ++r) {
                    int jg = jb + nb * 16 + quad * 4 + r;
                    stB[nb][r] = (jg <= rbaseB + col) ? fmaf(stB[nb][r], SCALE2, -M0)
                                                      : NEG_BIG;
                }
        } else {
#pragma unroll
            for (int nb = 0; nb < 4; ++nb)
#pragma unroll
                for (int r = 0; r < 4; ++r)
                    stB[nb][r] = fmaf(stB[nb][r], SCALE2, -M0);
        }
#pragma unroll
        for (int nb = 0; nb < 4; ++nb) {
#pragma unroll
            for (int r = 0; r < 4; ++r)
                stB[nb][r] = exp2f(stB[nb][r]);
            lsumB4 += stB[nb];
        }
#pragma unroll
        for (int r = 0; r < 4; ++r) {
            paloB[r]     = (bf16)stB[0][r];
            paloB[4 + r] = (bf16)stB[2][r];
            pahiB[r]     = (bf16)stB[1][r];
            pahiB[4 + r] = (bf16)stB[3][r];
        }

        // PV: each vlo/vhi read feeds BOTH q-groups (V k-permuted in storage)
#pragma unroll
        for (int n2 = 0; n2 < 6; ++n2) {
            const bf16* vrow = &ldsV[(n2 * 16 + col) * VSTR];
            bf16x8 vlo = *(const bf16x8*)&vrow[quad * 8];
            bf16x8 vhi = *(const bf16x8*)&vrow[32 + quad * 8];
            if (aAct) {
                oA[n2] = __builtin_amdgcn_mfma_f32_16x16x32_bf16(vlo, paloA, oA[n2], 0, 0, 0);
                oA[n2] = __builtin_amdgcn_mfma_f32_16x16x32_bf16(vhi, pahiA, oA[n2], 0, 0, 0);
            }
            oB[n2] = __builtin_amdgcn_mfma_f32_16x16x32_bf16(vlo, paloB, oB[n2], 0, 0, 0);
            oB[n2] = __builtin_amdgcn_mfma_f32_16x16x32_bf16(vhi, pahiB, oB[n2], 0, 0, 0);
        }
    }

    float lsumA = (lsumA4[0] + lsumA4[1]) + (lsumA4[2] + lsumA4[3]);
    lsumA += __shfl_xor(lsumA, 16, 64);
    lsumA += __shfl_xor(lsumA, 32, 64);
    float linvA = 1.0f / lsumA;
    float lsumB = (lsumB4[0] + lsumB4[1]) + (lsumB4[2] + lsumB4[3]);
    lsumB += __shfl_xor(lsumB, 16, 64);
    lsumB += __shfl_xor(lsumB, 32, 64);
    float linvB = 1.0f / lsumB;
#pragma unroll
    for (int n2 = 0; n2 < 6; ++n2) {
        bf16x4 pkA = {(bf16)(oA[n2][0] * linvA), (bf16)(oA[n2][1] * linvA),
                      (bf16)(oA[n2][2] * linvA), (bf16)(oA[n2][3] * linvA)};
        *(bf16x4*)&yb[(size_t)(rbaseA + col) * C_ + h * HS_ + n2 * 16 + quad * 4] = pkA;
        bf16x4 pkB = {(bf16)(oB[n2][0] * linvB), (bf16)(oB[n2][1] * linvB),
                      (bf16)(oB[n2][2] * linvB), (bf16)(oB[n2][3] * linvB)};
        *(bf16x4*)&yb[(size_t)(rbaseB + col) * C_ + h * HS_ + n2 * 16 + quad * 4] = pkB;
    }
}

// ---------------------------------------------------------------------------
extern "C" void kernel_launch(void* const* d_in, const int* in_sizes, int n_in,
                              void* d_out, int out_size, void* d_ws, size_t ws_size,
                              hipStream_t stream) {
    (void)in_sizes; (void)n_in;
    const float* x      = (const float*)d_in[0];
    const float* W_attn = (const float*)d_in[1];
    const float* b_attn = (const float*)d_in[2];
    const float* W_proj = (const float*)d_in[3];
    const float* b_proj = (const float*)d_in[4];
    float* out = (float*)d_out;

    size_t e_wta = (size_t)QKN_ * C_;
    size_t e_wtp = (size_t)C_ * C_;
    size_t a_qkv = e_wta + e_wtp;
    size_t a_vt  = a_qkv + (size_t)M_ * QKN_;
    size_t a_yb  = a_vt + (size_t)M_ * C_;
    size_t needA = (a_yb + (size_t)M_ * C_) * sizeof(bf16);   // 67.6 MB
    size_t b_qkv = e_wta + e_wtp;
    size_t b_vt  = b_qkv + (size_t)T_ * QKN_;
    size_t b_yb  = b_vt + (size_t)T_ * C_;
    size_t needB = (b_yb + (size_t)T_ * C_) * sizeof(bf16);   // 20.4 MB

    if (ws_size >= needA) {
        bf16* Wt_attn = (bf16*)d_ws;
        bf16* Wt_proj = (bf16*)d_ws + e_wta;
        bf16* qkv     = (bf16*)d_ws + a_qkv;
        bf16* Vt      = (bf16*)d_ws + a_vt;
        bf16* yb      = (bf16*)d_ws + a_yb;
        bf16* xb      = yb;  // alias (xb dead before attn writes yb)
        prep_kernel<<<dim3(CONV_BLKS + TA_BLKS + TP_BLKS), 256, 0, stream>>>(
            x, xb, W_attn, Wt_attn, W_proj, Wt_proj);
        gemm_qkv<<<dim3(QKN_ / 128, M_ / 128), 256, 0, stream>>>(
            xb, Wt_attn, b_attn, qkv, Vt, M_, QKN_, C_);
        attn_kernel<<<dim3(16 * H_ * B_), 256, 0, stream>>>(qkv, Vt, yb, H_ * B_);
        gemm_proj<<<dim3(C_ / 128, M_ / 128), 256, 0, stream>>>(
            yb, Wt_proj, b_proj, out, M_, C_, C_);
    } else if (ws_size >= needB) {
        bf16* Wt_attn = (bf16*)d_ws;
        bf16* Wt_proj = (bf16*)d_ws + e_wta;
        bf16* qkv     = (bf16*)d_ws + b_qkv;
        bf16* Vt      = (bf16*)d_ws + b_vt;
        bf16* yb      = (bf16*)d_ws + b_yb;
        bf16* xb      = yb;  // alias per-batch
        transpose_kernel<<<dim3(QKN_ / 32, C_ / 32), dim3(32, 8), 0, stream>>>(W_attn, Wt_attn, C_, QKN_);
        transpose_kernel<<<dim3(C_ / 32, C_ / 32), dim3(32, 8), 0, stream>>>(W_proj, Wt_proj, C_, C_);
        for (int b = 0; b < B_; ++b) {
            const float* xf = x + (size_t)b * T_ * C_;
            float* outb     = out + (size_t)b * T_ * C_;
            convert_bf16_kernel<<<dim3(T_ * C_ / 8 / 256), 256, 0, stream>>>(xf, xb, T_ * C_ / 8);
            gemm_qkv<<<dim3(QKN_ / 128, T_ / 128), 256, 0, stream>>>(
                xb, Wt_attn, b_attn, qkv, Vt, T_, QKN_, C_);
            attn_kernel<<<dim3(16 * H_), 256, 0, stream>>>(qkv, Vt, yb, H_);
            gemm_proj<<<dim3(C_ / 128, T_ / 128), 256, 0, stream>>>(
                yb, Wt_proj, b_proj, outb, T_, C_, C_);
        }
    } else {
        sentinel_kernel<<<(out_size + 255) / 256, 256, 0, stream>>>(out, out_size);
    }
}

// Round 9
// 205.759 us; speedup vs baseline: 1.1247x; 1.1247x over previous
//
#include <hip/hip_runtime.h>

typedef __bf16 bf16;
typedef __attribute__((ext_vector_type(4))) __bf16 bf16x4;
typedef __attribute__((ext_vector_type(8))) __bf16 bf16x8;
typedef __attribute__((ext_vector_type(4))) float f32x4;

#define B_   4
#define T_   2048
#define C_   768
#define H_   8
#define HS_  96
#define M_   (B_ * T_)      /* 8192 */
#define QKN_ (3 * C_)       /* 2304 */

#define NEG_BIG (-1e30f)

// LDS strides (elements) for attn tiles
#define KSTR 104   /* 64x(96) K tile rows, padded 96->104 */
#define VSTR 72    /* 96x(64) Vt tile rows, padded 64->72 */

// ---------------------------------------------------------------------------
// async global->LDS, 16B per lane. LDS dest must be wave-uniform base;
// HW writes base + lane*16 (m104). Global addr is per-lane.
// ---------------------------------------------------------------------------
__device__ __forceinline__ void gload_lds16(const bf16* g, bf16* l) {
    __builtin_amdgcn_global_load_lds(
        (const __attribute__((address_space(1))) uint32_t*)g,
        (__attribute__((address_space(3))) uint32_t*)l,
        16, 0, 0);
}

__device__ __forceinline__ bf16x8 cvt8(f32x4 v0, f32x4 v1) {
    bf16x8 o;
#pragma unroll
    for (int i = 0; i < 4; ++i) { o[i] = (bf16)v0[i]; o[4 + i] = (bf16)v1[i]; }
    return o;
}

// ---------------------------------------------------------------------------
// Transpose + convert: W[R][Cn] (fp32) -> Wt[Cn][R] (bf16)  (path-B fallback)
// ---------------------------------------------------------------------------
__global__ void transpose_kernel(const float* __restrict__ W, bf16* __restrict__ Wt,
                                 int R, int Cn) {
    __shared__ bf16 tile[32][33];
    int tx = threadIdx.x, ty = threadIdx.y;
    int x  = blockIdx.x * 32 + tx;
    int y0 = blockIdx.y * 32;
#pragma unroll
    for (int j = 0; j < 32; j += 8)
        tile[ty + j][tx] = (bf16)W[(size_t)(y0 + ty + j) * Cn + x];
    __syncthreads();
    int y2 = blockIdx.x * 32;
    int x2 = y0 + tx;
#pragma unroll
    for (int j = 0; j < 32; j += 8)
        Wt[(size_t)(y2 + ty + j) * R + x2] = tile[tx][ty + j];
}

// ---------------------------------------------------------------------------
__global__ void sentinel_kernel(float* __restrict__ out, int n) {
    int i = blockIdx.x * 256 + threadIdx.x;
    if (i < n) out[i] = 12345.0f;
}

// ---------------------------------------------------------------------------
// One-shot fp32 -> bf16 convert (x -> xb)  (path-B fallback)
// ---------------------------------------------------------------------------
__global__ __launch_bounds__(256) void convert_bf16_kernel(const float* __restrict__ in,
                                                           bf16* __restrict__ out,
                                                           int n8) {
    int i = blockIdx.x * 256 + threadIdx.x;
    if (i >= n8) return;
    const float* p = in + (size_t)i * 8;
    f32x4 a = *(const f32x4*)p;
    f32x4 b = *(const f32x4*)(p + 4);
    *(bf16x8*)&out[(size_t)i * 8] = cvt8(a, b);
}

// ---------------------------------------------------------------------------
// Merged prep: convert x->xb (bf16) + transpose both weights, one launch.
// ---------------------------------------------------------------------------
#define CONV_BLKS (M_ * C_ / 8 / 256)          /* 3072 */
#define TA_BX (QKN_ / 32)                      /* 72 */
#define TA_BLKS (TA_BX * (C_ / 32))            /* 1728 */
#define TP_BX (C_ / 32)                        /* 24 */
#define TP_BLKS (TP_BX * (C_ / 32))            /* 576 */

__device__ __forceinline__ void transpose_body(bf16 (*tile)[33],
                                               const float* __restrict__ W,
                                               bf16* __restrict__ Wt,
                                               int R, int Cn, int bx, int by, int tid) {
    int tx = tid & 31, ty = tid >> 5;
    int x  = bx * 32 + tx;
    int y0 = by * 32;
#pragma unroll
    for (int j = 0; j < 32; j += 8)
        tile[ty + j][tx] = (bf16)W[(size_t)(y0 + ty + j) * Cn + x];
    __syncthreads();
    int y2 = bx * 32;
    int x2 = y0 + tx;
#pragma unroll
    for (int j = 0; j < 32; j += 8)
        Wt[(size_t)(y2 + ty + j) * R + x2] = tile[tx][ty + j];
}

__global__ __launch_bounds__(256) void prep_kernel(const float* __restrict__ x,
                                                   bf16* __restrict__ xb,
                                                   const float* __restrict__ Wa,
                                                   bf16* __restrict__ Wta,
                                                   const float* __restrict__ Wp,
                                                   bf16* __restrict__ Wtp) {
    __shared__ bf16 tile[32][33];
    int bid = blockIdx.x;
    int tid = threadIdx.x;
    if (bid < CONV_BLKS) {
        int i = bid * 256 + tid;
        const float* p = x + (size_t)i * 8;
        f32x4 a = *(const f32x4*)p;
        f32x4 b = *(const f32x4*)(p + 4);
        *(bf16x8*)&xb[(size_t)i * 8] = cvt8(a, b);
    } else if (bid < CONV_BLKS + TA_BLKS) {
        int t = bid - CONV_BLKS;
        transpose_body(tile, Wa, Wta, C_, QKN_, t % TA_BX, t / TA_BX, tid);
    } else {
        int t = bid - CONV_BLKS - TA_BLKS;
        transpose_body(tile, Wp, Wtp, C_, C_, t % TP_BX, t / TP_BX, tid);
    }
}

#define TILE_ELEMS (128 * 64)

// ---------------------------------------------------------------------------
// GEMM1 (T3 minimum 2-phase): qkv[M][2304] = xb[M][768](bf16) @ Bt^T + b.
// Vt epilogue k-permutes t within each 64-tile:
//   p(k) = (k&3) + (((k>>2)&7)<<3) + ((k>>5)<<2)
// so attn's permuted-k PV reads V as contiguous b128 (conflict-free).
// ---------------------------------------------------------------------------
__global__ __launch_bounds__(256) void gemm_qkv(const bf16* __restrict__ A,
                                                const bf16* __restrict__ Bt,
                                                const float* __restrict__ bias,
                                                bf16* __restrict__ Cmat,
                                                bf16* __restrict__ Vt,
                                                int M, int N, int K) {
    __shared__ bf16 lda[2 * TILE_ELEMS];
    __shared__ bf16 ldb[2 * TILE_ELEMS];
    int tid  = threadIdx.x;
    int w    = tid >> 6;
    int lane = tid & 63;
    int col  = lane & 15, quad = lane >> 4;
    int wr   = w >> 1, wc = w & 1;
    int m0   = blockIdx.y * 128, n0 = blockIdx.x * 128;

    int srow = lane >> 3;
    int scol = (lane & 7) * 8;
    const bf16* gA[4]; const bf16* gB[4]; bf16* lA[4]; bf16* lB[4];
#pragma unroll
    for (int i = 0; i < 4; ++i) {
        int seg = w * 4 + i;
        int row = seg * 8 + srow;
        gA[i] = &A[(size_t)(m0 + row) * K + scol];
        gB[i] = &Bt[(size_t)(n0 + row) * K + scol];
        lA[i] = &lda[seg * 512];
        lB[i] = &ldb[seg * 512];
    }

    const f32x4 zero = {0.f, 0.f, 0.f, 0.f};
    f32x4 acc[4][4];
#pragma unroll
    for (int mr = 0; mr < 4; ++mr)
#pragma unroll
        for (int nc = 0; nc < 4; ++nc) acc[mr][nc] = zero;

#pragma unroll
    for (int i = 0; i < 4; ++i) {
        gload_lds16(gA[i], lA[i]);
        gload_lds16(gB[i], lB[i]);
    }
    __syncthreads();

    int cur = 0;
    for (int k0 = 0; k0 < K; k0 += 64) {
        int nxt = cur ^ 1;
        if (k0 + 64 < K) {
#pragma unroll
            for (int i = 0; i < 4; ++i) {
                gload_lds16(gA[i] + k0 + 64, lA[i] + nxt * TILE_ELEMS);
                gload_lds16(gB[i] + k0 + 64, lB[i] + nxt * TILE_ELEMS);
            }
        }
        const bf16* la = &lda[cur * TILE_ELEMS];
        const bf16* lb = &ldb[cur * TILE_ELEMS];
#pragma unroll
        for (int ks = 0; ks < 2; ++ks) {
            bf16x8 af[4], bfr[4];
#pragma unroll
            for (int t = 0; t < 4; ++t) {
                af[t]  = *(const bf16x8*)&la[(wr * 64 + t * 16 + col) * 64 + ks * 32 + quad * 8];
                bfr[t] = *(const bf16x8*)&lb[(wc * 64 + t * 16 + col) * 64 + ks * 32 + quad * 8];
            }
#pragma unroll
            for (int mr = 0; mr < 4; ++mr)
#pragma unroll
                for (int nc = 0; nc < 4; ++nc)
                    acc[mr][nc] = __builtin_amdgcn_mfma_f32_16x16x32_bf16(
                        af[mr], bfr[nc], acc[mr][nc], 0, 0, 0);
        }
        __syncthreads();
        cur = nxt;
    }

#pragma unroll
    for (int nc = 0; nc < 4; ++nc) {
        int n = n0 + wc * 64 + nc * 16 + col;
        float bv = bias[n];
#pragma unroll
        for (int mr = 0; mr < 4; ++mr) {
#pragma unroll
            for (int r = 0; r < 4; ++r) {
                int row = m0 + wr * 64 + mr * 16 + quad * 4 + r;
                Cmat[(size_t)row * N + n] = (bf16)(acc[mr][nc][r] + bv);
            }
        }
    }
    if (n0 >= 2 * C_) {
        int batch = m0 >> 11;
        bf16* Vtb = Vt + (size_t)batch * C_ * T_;
        int t0 = (m0 & 2047) + wr * 64;
#pragma unroll
        for (int nc = 0; nc < 4; ++nc) {
            int n  = n0 + wc * 64 + nc * 16 + col;
            int vc = n - 2 * C_;
            float bv = bias[n];
#pragma unroll
            for (int mr = 0; mr < 4; ++mr) {
                int t  = t0 + mr * 16 + quad * 4;
                int tb = t & ~63;                 // 64-tile base
                int a  = (t >> 2) & 15;           // 4-chunk index in tile
                int ts = tb + ((a & 7) << 3) + ((a >> 3) << 2);  // permuted base
                bf16x4 pk = {(bf16)(acc[mr][nc][0] + bv), (bf16)(acc[mr][nc][1] + bv),
                             (bf16)(acc[mr][nc][2] + bv), (bf16)(acc[mr][nc][3] + bv)};
                *(bf16x4*)&Vtb[(size_t)vc * T_ + ts] = pk;
            }
        }
    }
}

// ---------------------------------------------------------------------------
// GEMM2 (T3 minimum 2-phase): out[M][768](fp32) = yb[M][768](bf16) @ Bt^T + b.
// ---------------------------------------------------------------------------
__global__ __launch_bounds__(256) void gemm_proj(const bf16* __restrict__ A,
                                                 const bf16* __restrict__ Bt,
                                                 const float* __restrict__ bias,
                                                 float* __restrict__ Cmat,
                                                 int M, int N, int K) {
    __shared__ bf16 lda[2 * TILE_ELEMS];
    __shared__ bf16 ldb[2 * TILE_ELEMS];
    int tid  = threadIdx.x;
    int w    = tid >> 6;
    int lane = tid & 63;
    int col  = lane & 15, quad = lane >> 4;
    int wr   = w >> 1, wc = w & 1;
    int m0   = blockIdx.y * 128, n0 = blockIdx.x * 128;

    int srow = lane >> 3;
    int scol = (lane & 7) * 8;
    const bf16* gA[4]; const bf16* gB[4]; bf16* lA[4]; bf16* lB[4];
#pragma unroll
    for (int i = 0; i < 4; ++i) {
        int seg = w * 4 + i;
        int row = seg * 8 + srow;
        gA[i] = &A[(size_t)(m0 + row) * K + scol];
        gB[i] = &Bt[(size_t)(n0 + row) * K + scol];
        lA[i] = &lda[seg * 512];
        lB[i] = &ldb[seg * 512];
    }

    const f32x4 zero = {0.f, 0.f, 0.f, 0.f};
    f32x4 acc[4][4];
#pragma unroll
    for (int mr = 0; mr < 4; ++mr)
#pragma unroll
        for (int nc = 0; nc < 4; ++nc) acc[mr][nc] = zero;

#pragma unroll
    for (int i = 0; i < 4; ++i) {
        gload_lds16(gA[i], lA[i]);
        gload_lds16(gB[i], lB[i]);
    }
    __syncthreads();

    int cur = 0;
    for (int k0 = 0; k0 < K; k0 += 64) {
        int nxt = cur ^ 1;
        if (k0 + 64 < K) {
#pragma unroll
            for (int i = 0; i < 4; ++i) {
                gload_lds16(gA[i] + k0 + 64, lA[i] + nxt * TILE_ELEMS);
                gload_lds16(gB[i] + k0 + 64, lB[i] + nxt * TILE_ELEMS);
            }
        }
        const bf16* la = &lda[cur * TILE_ELEMS];
        const bf16* lb = &ldb[cur * TILE_ELEMS];
#pragma unroll
        for (int ks = 0; ks < 2; ++ks) {
            bf16x8 af[4], bfr[4];
#pragma unroll
            for (int t = 0; t < 4; ++t) {
                af[t]  = *(const bf16x8*)&la[(wr * 64 + t * 16 + col) * 64 + ks * 32 + quad * 8];
                bfr[t] = *(const bf16x8*)&lb[(wc * 64 + t * 16 + col) * 64 + ks * 32 + quad * 8];
            }
#pragma unroll
            for (int mr = 0; mr < 4; ++mr)
#pragma unroll
                for (int nc = 0; nc < 4; ++nc)
                    acc[mr][nc] = __builtin_amdgcn_mfma_f32_16x16x32_bf16(
                        af[mr], bfr[nc], acc[mr][nc], 0, 0, 0);
        }
        __syncthreads();
        cur = nxt;
    }

#pragma unroll
    for (int nc = 0; nc < 4; ++nc) {
        int n = n0 + wc * 64 + nc * 16 + col;
        float bv = bias[n];
#pragma unroll
        for (int mr = 0; mr < 4; ++mr) {
#pragma unroll
            for (int r = 0; r < 4; ++r) {
                int row = m0 + wr * 64 + mr * 16 + quad * 4 + r;
                Cmat[(size_t)row * N + n] = acc[mr][nc][r] + bv;
            }
        }
    }
}

// ---------------------------------------------------------------------------
// Fused causal flash attention — REVERTED to the r5 structure (measured
// 58.5 us: 1024 blocks, 4/CU co-residency; r8's 128-row tiles halved grid
// to 2/CU and regressed to 82.5 despite lower LDS traffic). One addition:
// T5 s_setprio around MFMA clusters (catalog m191: +4-7% for attn with
// independent blocks at different phases — exactly this regime; NOT applied
// to the lockstep GEMMs per m190).
// Static-exponent softmax, T14 prefetch, P-in-register permuted-k PV,
// k-permuted V store, f32x4 lsum chains, heavy-first blocks.
// ---------------------------------------------------------------------------
__global__ __launch_bounds__(256) void attn_kernel(const bf16* __restrict__ qkv,
                                                   const bf16* __restrict__ Vt,
                                                   bf16* __restrict__ y,
                                                   int nGroups) {
    __shared__ bf16 ldsK[64 * KSTR];
    __shared__ bf16 ldsV[96 * VSTR];
    const int bid  = blockIdx.x;
    const int qt   = 31 - bid / nGroups;      // heavy blocks first
    const int g    = bid % nGroups;
    const int h    = g & 7, b = g >> 3;
    const int tid  = threadIdx.x;
    const int w    = tid >> 6, lane = tid & 63;
    const int col  = lane & 15, quad = lane >> 4;
    const float SCALE2 = 0.10206207261596577f * 1.4426950408889634f; // scale*log2e
    const float M0 = 24.0f;                    // static exponent shift (exact)
    const f32x4 zero = {0.f, 0.f, 0.f, 0.f};

    const bf16* qkvb = qkv + (size_t)b * T_ * QKN_;
    const bf16* Vtbh = Vt + (size_t)(b * H_ + h) * HS_ * T_;
    bf16* yb  = y + (size_t)b * T_ * C_;

    const int rbase = qt * 64 + w * 16;

    bf16x8 qf[3];
#pragma unroll
    for (int c = 0; c < 3; ++c)
        qf[c] = *(const bf16x8*)&qkvb[(size_t)(rbase + col) * QKN_ + h * HS_ + c * 32 + quad * 8];

    const bf16* pK[3]; const bf16* pV[3];
    bf16 *dK[3], *dV[3];
#pragma unroll
    for (int i = 0; i < 3; ++i) {
        int chunk = i * 256 + tid;
        int rK = chunk / 12, cK = chunk - rK * 12;
        pK[i] = qkvb + (size_t)rK * QKN_ + C_ + h * HS_ + cK * 8;
        dK[i] = &ldsK[rK * KSTR + cK * 8];
        int rV = chunk >> 3, cV = chunk & 7;
        pV[i] = Vtbh + (size_t)rV * T_ + cV * 8;
        dV[i] = &ldsV[rV * VSTR + cV * 8];
    }

    f32x4 o[6];
#pragma unroll
    for (int n2 = 0; n2 < 6; ++n2) o[n2] = zero;
    f32x4 lsum4 = zero;

    // prologue: prefetch jt=0 K/V into registers
    bf16x8 kreg[3], vreg[3];
#pragma unroll
    for (int i = 0; i < 3; ++i) {
        kreg[i] = *(const bf16x8*)pK[i];
        vreg[i] = *(const bf16x8*)pV[i];
        pK[i] += (size_t)64 * QKN_;
        pV[i] += 64;
    }

    const int njt = qt + 1;
    for (int jt = 0; jt < njt; ++jt) {
        int jb = jt * 64;
        __syncthreads();
        // write-late: regs -> LDS
#pragma unroll
        for (int i = 0; i < 3; ++i) {
            *(bf16x8*)dK[i] = kreg[i];
            *(bf16x8*)dV[i] = vreg[i];
        }
        __syncthreads();
        // issue-early: next tile's global loads fly under compute below
        if (jt + 1 < njt) {
#pragma unroll
            for (int i = 0; i < 3; ++i) {
                kreg[i] = *(const bf16x8*)pK[i];
                vreg[i] = *(const bf16x8*)pV[i];
                pK[i] += (size_t)64 * QKN_;
                pV[i] += 64;
            }
        }

        // QK^T: kf loaded per-nb (short live-range); T5 boost for MFMA cluster
        f32x4 st[4];
        __builtin_amdgcn_s_setprio(1);
#pragma unroll
        for (int nb = 0; nb < 4; ++nb) {
            st[nb] = zero;
#pragma unroll
            for (int c = 0; c < 3; ++c) {
                bf16x8 kf = *(const bf16x8*)&ldsK[(nb * 16 + col) * KSTR + c * 32 + quad * 8];
                st[nb] = __builtin_amdgcn_mfma_f32_16x16x32_bf16(
                    kf, qf[c], st[nb], 0, 0, 0);
            }
        }
        __builtin_amdgcn_s_setprio(0);

        if (jt == njt - 1) {
#pragma unroll
            for (int nb = 0; nb < 4; ++nb)
#pragma unroll
                for (int r = 0; r < 4; ++r) {
                    int jg = jb + nb * 16 + quad * 4 + r;
                    st[nb][r] = (jg <= rbase + col) ? fmaf(st[nb][r], SCALE2, -M0)
                                                    : NEG_BIG;
                }
        } else {
#pragma unroll
            for (int nb = 0; nb < 4; ++nb)
#pragma unroll
                for (int r = 0; r < 4; ++r)
                    st[nb][r] = fmaf(st[nb][r], SCALE2, -M0);
        }

#pragma unroll
        for (int nb = 0; nb < 4; ++nb) {
#pragma unroll
            for (int r = 0; r < 4; ++r)
                st[nb][r] = exp2f(st[nb][r]);
            lsum4 += st[nb];              // 4 independent FP chains
        }

        // Pack P as permuted-k B-operands (st stays in registers):
        // palo slot quad*8+j <-> k = (j<4?0:2)*16 + quad*4 + (j&3)
        // pahi slot quad*8+j <-> k = (j<4?1:3)*16 + quad*4 + (j&3)
        bf16x8 palo, pahi;
#pragma unroll
        for (int r = 0; r < 4; ++r) {
            palo[r]     = (bf16)st[0][r];
            palo[4 + r] = (bf16)st[2][r];
            pahi[r]     = (bf16)st[1][r];
            pahi[4 + r] = (bf16)st[3][r];
        }

        // V is k-permuted in storage: matching operand = contiguous b128
        __builtin_amdgcn_s_setprio(1);
#pragma unroll
        for (int n2 = 0; n2 < 6; ++n2) {
            const bf16* vrow = &ldsV[(n2 * 16 + col) * VSTR];
            bf16x8 vlo = *(const bf16x8*)&vrow[quad * 8];
            bf16x8 vhi = *(const bf16x8*)&vrow[32 + quad * 8];
            o[n2] = __builtin_amdgcn_mfma_f32_16x16x32_bf16(vlo, palo, o[n2], 0, 0, 0);
            o[n2] = __builtin_amdgcn_mfma_f32_16x16x32_bf16(vhi, pahi, o[n2], 0, 0, 0);
        }
        __builtin_amdgcn_s_setprio(0);
    }

    float lsum = (lsum4[0] + lsum4[1]) + (lsum4[2] + lsum4[3]);
    lsum += __shfl_xor(lsum, 16, 64);
    lsum += __shfl_xor(lsum, 32, 64);
    float linv = 1.0f / lsum;
#pragma unroll
    for (int n2 = 0; n2 < 6; ++n2) {
        bf16x4 pk = {(bf16)(o[n2][0] * linv), (bf16)(o[n2][1] * linv),
                     (bf16)(o[n2][2] * linv), (bf16)(o[n2][3] * linv)};
        *(bf16x4*)&yb[(size_t)(rbase + col) * C_ + h * HS_ + n2 * 16 + quad * 4] = pk;
    }
}

// ---------------------------------------------------------------------------
extern "C" void kernel_launch(void* const* d_in, const int* in_sizes, int n_in,
                              void* d_out, int out_size, void* d_ws, size_t ws_size,
                              hipStream_t stream) {
    (void)in_sizes; (void)n_in;
    const float* x      = (const float*)d_in[0];
    const float* W_attn = (const float*)d_in[1];
    const float* b_attn = (const float*)d_in[2];
    const float* W_proj = (const float*)d_in[3];
    const float* b_proj = (const float*)d_in[4];
    float* out = (float*)d_out;

    size_t e_wta = (size_t)QKN_ * C_;
    size_t e_wtp = (size_t)C_ * C_;
    size_t a_qkv = e_wta + e_wtp;
    size_t a_vt  = a_qkv + (size_t)M_ * QKN_;
    size_t a_yb  = a_vt + (size_t)M_ * C_;
    size_t needA = (a_yb + (size_t)M_ * C_) * sizeof(bf16);   // 67.6 MB
    size_t b_qkv = e_wta + e_wtp;
    size_t b_vt  = b_qkv + (size_t)T_ * QKN_;
    size_t b_yb  = b_vt + (size_t)T_ * C_;
    size_t needB = (b_yb + (size_t)T_ * C_) * sizeof(bf16);   // 20.4 MB

    if (ws_size >= needA) {
        bf16* Wt_attn = (bf16*)d_ws;
        bf16* Wt_proj = (bf16*)d_ws + e_wta;
        bf16* qkv     = (bf16*)d_ws + a_qkv;
        bf16* Vt      = (bf16*)d_ws + a_vt;
        bf16* yb      = (bf16*)d_ws + a_yb;
        bf16* xb      = yb;  // alias (xb dead before attn writes yb)
        prep_kernel<<<dim3(CONV_BLKS + TA_BLKS + TP_BLKS), 256, 0, stream>>>(
            x, xb, W_attn, Wt_attn, W_proj, Wt_proj);
        gemm_qkv<<<dim3(QKN_ / 128, M_ / 128), 256, 0, stream>>>(
            xb, Wt_attn, b_attn, qkv, Vt, M_, QKN_, C_);
        attn_kernel<<<dim3(32 * H_ * B_), 256, 0, stream>>>(qkv, Vt, yb, H_ * B_);
        gemm_proj<<<dim3(C_ / 128, M_ / 128), 256, 0, stream>>>(
            yb, Wt_proj, b_proj, out, M_, C_, C_);
    } else if (ws_size >= needB) {
        bf16* Wt_attn = (bf16*)d_ws;
        bf16* Wt_proj = (bf16*)d_ws + e_wta;
        bf16* qkv     = (bf16*)d_ws + b_qkv;
        bf16* Vt      = (bf16*)d_ws + b_vt;
        bf16* yb      = (bf16*)d_ws + b_yb;
        bf16* xb      = yb;  // alias per-batch
        transpose_kernel<<<dim3(QKN_ / 32, C_ / 32), dim3(32, 8), 0, stream>>>(W_attn, Wt_attn, C_, QKN_);
        transpose_kernel<<<dim3(C_ / 32, C_ / 32), dim3(32, 8), 0, stream>>>(W_proj, Wt_proj, C_, C_);
        for (int b = 0; b < B_; ++b) {
            const float* xf = x + (size_t)b * T_ * C_;
            float* outb     = out + (size_t)b * T_ * C_;
            convert_bf16_kernel<<<dim3(T_ * C_ / 8 / 256), 256, 0, stream>>>(xf, xb, T_ * C_ / 8);
            gemm_qkv<<<dim3(QKN_ / 128, T_ / 128), 256, 0, stream>>>(
                xb, Wt_attn, b_attn, qkv, Vt, T_, QKN_, C_);
            attn_kernel<<<dim3(32 * H_), 256, 0, stream>>>(qkv, Vt, yb, H_);
            gemm_proj<<<dim3(C_ / 128, T_ / 128), 256, 0, stream>>>(
                yb, Wt_proj, b_proj, outb, T_, C_, C_);
        }
    } else {
        sentinel_kernel<<<(out_size + 255) / 256, 256, 0, stream>>>(out, out_size);
    }
}

// Round 10
// 200.091 us; speedup vs baseline: 1.1566x; 1.0283x over previous
//
#include <hip/hip_runtime.h>

typedef __bf16 bf16;
typedef __attribute__((ext_vector_type(4))) __bf16 bf16x4;
typedef __attribute__((ext_vector_type(8))) __bf16 bf16x8;
typedef __attribute__((ext_vector_type(4))) float f32x4;

#define B_   4
#define T_   2048
#define C_   768
#define H_   8
#define HS_  96
#define M_   (B_ * T_)      /* 8192 */
#define QKN_ (3 * C_)       /* 2304 */

#define NEG_BIG (-1e30f)

// LDS strides (elements) for attn tiles
#define KSTR 104   /* 64x(96) K tile rows, padded 96->104 */
#define VSTR 72    /* 96x(64) Vt tile rows, padded 64->72 */

// ---------------------------------------------------------------------------
// async global->LDS, 16B per lane. LDS dest must be wave-uniform base;
// HW writes base + lane*16 (m104). Global addr is per-lane.
// ---------------------------------------------------------------------------
__device__ __forceinline__ void gload_lds16(const bf16* g, bf16* l) {
    __builtin_amdgcn_global_load_lds(
        (const __attribute__((address_space(1))) uint32_t*)g,
        (__attribute__((address_space(3))) uint32_t*)l,
        16, 0, 0);
}

__device__ __forceinline__ bf16x8 cvt8(f32x4 v0, f32x4 v1) {
    bf16x8 o;
#pragma unroll
    for (int i = 0; i < 4; ++i) { o[i] = (bf16)v0[i]; o[4 + i] = (bf16)v1[i]; }
    return o;
}

// ---------------------------------------------------------------------------
// Transpose + convert: W[R][Cn] (fp32) -> Wt[Cn][R] (bf16)  (path-B fallback)
// ---------------------------------------------------------------------------
__global__ void transpose_kernel(const float* __restrict__ W, bf16* __restrict__ Wt,
                                 int R, int Cn) {
    __shared__ bf16 tile[32][33];
    int tx = threadIdx.x, ty = threadIdx.y;
    int x  = blockIdx.x * 32 + tx;
    int y0 = blockIdx.y * 32;
#pragma unroll
    for (int j = 0; j < 32; j += 8)
        tile[ty + j][tx] = (bf16)W[(size_t)(y0 + ty + j) * Cn + x];
    __syncthreads();
    int y2 = blockIdx.x * 32;
    int x2 = y0 + tx;
#pragma unroll
    for (int j = 0; j < 32; j += 8)
        Wt[(size_t)(y2 + ty + j) * R + x2] = tile[tx][ty + j];
}

// ---------------------------------------------------------------------------
__global__ void sentinel_kernel(float* __restrict__ out, int n) {
    int i = blockIdx.x * 256 + threadIdx.x;
    if (i < n) out[i] = 12345.0f;
}

// ---------------------------------------------------------------------------
// One-shot fp32 -> bf16 convert (x -> xb)  (path-B fallback)
// ---------------------------------------------------------------------------
__global__ __launch_bounds__(256) void convert_bf16_kernel(const float* __restrict__ in,
                                                           bf16* __restrict__ out,
                                                           int n8) {
    int i = blockIdx.x * 256 + threadIdx.x;
    if (i >= n8) return;
    const float* p = in + (size_t)i * 8;
    f32x4 a = *(const f32x4*)p;
    f32x4 b = *(const f32x4*)(p + 4);
    *(bf16x8*)&out[(size_t)i * 8] = cvt8(a, b);
}

// ---------------------------------------------------------------------------
// Merged prep: convert x->xb (bf16) + transpose both weights, one launch.
// ---------------------------------------------------------------------------
#define CONV_BLKS (M_ * C_ / 8 / 256)          /* 3072 */
#define TA_BX (QKN_ / 32)                      /* 72 */
#define TA_BLKS (TA_BX * (C_ / 32))            /* 1728 */
#define TP_BX (C_ / 32)                        /* 24 */
#define TP_BLKS (TP_BX * (C_ / 32))            /* 576 */

__device__ __forceinline__ void transpose_body(bf16 (*tile)[33],
                                               const float* __restrict__ W,
                                               bf16* __restrict__ Wt,
                                               int R, int Cn, int bx, int by, int tid) {
    int tx = tid & 31, ty = tid >> 5;
    int x  = bx * 32 + tx;
    int y0 = by * 32;
#pragma unroll
    for (int j = 0; j < 32; j += 8)
        tile[ty + j][tx] = (bf16)W[(size_t)(y0 + ty + j) * Cn + x];
    __syncthreads();
    int y2 = bx * 32;
    int x2 = y0 + tx;
#pragma unroll
    for (int j = 0; j < 32; j += 8)
        Wt[(size_t)(y2 + ty + j) * R + x2] = tile[tx][ty + j];
}

__global__ __launch_bounds__(256) void prep_kernel(const float* __restrict__ x,
                                                   bf16* __restrict__ xb,
                                                   const float* __restrict__ Wa,
                                                   bf16* __restrict__ Wta,
                                                   const float* __restrict__ Wp,
                                                   bf16* __restrict__ Wtp) {
    __shared__ bf16 tile[32][33];
    int bid = blockIdx.x;
    int tid = threadIdx.x;
    if (bid < CONV_BLKS) {
        int i = bid * 256 + tid;
        const float* p = x + (size_t)i * 8;
        f32x4 a = *(const f32x4*)p;
        f32x4 b = *(const f32x4*)(p + 4);
        *(bf16x8*)&xb[(size_t)i * 8] = cvt8(a, b);
    } else if (bid < CONV_BLKS + TA_BLKS) {
        int t = bid - CONV_BLKS;
        transpose_body(tile, Wa, Wta, C_, QKN_, t % TA_BX, t / TA_BX, tid);
    } else {
        int t = bid - CONV_BLKS - TA_BLKS;
        transpose_body(tile, Wp, Wtp, C_, C_, t % TP_BX, t / TP_BX, tid);
    }
}

#define TILE_ELEMS (128 * 64)

// ---------------------------------------------------------------------------
// GEMM1: qkv[M][2304] = xb[M][768](bf16) @ Bt^T + b.
// r10 changes (T4 + T2, both GEMMs):
//  * counted vmcnt: raw s_barrier + "s_waitcnt vmcnt(8)" — prefetched tile
//    t+1 loads stay in flight across the WHOLE next iteration instead of
//    being drained by __syncthreads' vmcnt(0) (T4, m218 +38-73%).
//  * XOR chunk swizzle: LDS slot (row, c) holds global chunk c^(row&7);
//    achieved source-side (gload_lds writes linearly, rule #21). Fragment
//    ds_read_b128 goes 16-way conflict -> throughput floor (T2; pays only
//    once T4 removes the stage stall — regime gate m252).
// Vt epilogue k-permutes t within each 64-tile (attn PV reads contiguous).
// ---------------------------------------------------------------------------
__global__ __launch_bounds__(256) void gemm_qkv(const bf16* __restrict__ A,
                                                const bf16* __restrict__ Bt,
                                                const float* __restrict__ bias,
                                                bf16* __restrict__ Cmat,
                                                bf16* __restrict__ Vt,
                                                int M, int N, int K) {
    __shared__ bf16 lda[2 * TILE_ELEMS];
    __shared__ bf16 ldb[2 * TILE_ELEMS];
    int tid  = threadIdx.x;
    int w    = tid >> 6;
    int lane = tid & 63;
    int col  = lane & 15, quad = lane >> 4;
    int wr   = w >> 1, wc = w & 1;
    int m0   = blockIdx.y * 128, n0 = blockIdx.x * 128;

    // staging: wave w owns segments w*4..w*4+3 (8 rows x 64 cols each).
    // Lane l -> row seg*8+(l>>3); SOURCE chunk (l&7)^srow (XOR swizzle);
    // LDS dest linear seg*1024B + l*16B (slot chunk l&7).
    int srow = lane >> 3;
    int scol = ((lane & 7) ^ srow) * 8;
    const bf16* gA[4]; const bf16* gB[4]; bf16* lA[4]; bf16* lB[4];
#pragma unroll
    for (int i = 0; i < 4; ++i) {
        int seg = w * 4 + i;
        int row = seg * 8 + srow;
        gA[i] = &A[(size_t)(m0 + row) * K + scol];
        gB[i] = &Bt[(size_t)(n0 + row) * K + scol];
        lA[i] = &lda[seg * 512];
        lB[i] = &ldb[seg * 512];
    }

    const f32x4 zero = {0.f, 0.f, 0.f, 0.f};
    f32x4 acc[4][4];
#pragma unroll
    for (int mr = 0; mr < 4; ++mr)
#pragma unroll
        for (int nc = 0; nc < 4; ++nc) acc[mr][nc] = zero;

    // prologue: stage tile 0 into buffer 0 (8 loads in flight, NOT drained)
#pragma unroll
    for (int i = 0; i < 4; ++i) {
        gload_lds16(gA[i], lA[i]);
        gload_lds16(gB[i], lB[i]);
    }

    int cur = 0;
    for (int k0 = 0; k0 < K; k0 += 64) {
        int nxt = cur ^ 1;
        if (k0 + 64 < K) {
            // issue next tile first; counted wait leaves those 8 in flight
#pragma unroll
            for (int i = 0; i < 4; ++i) {
                gload_lds16(gA[i] + k0 + 64, lA[i] + nxt * TILE_ELEMS);
                gload_lds16(gB[i] + k0 + 64, lB[i] + nxt * TILE_ELEMS);
            }
            asm volatile("s_waitcnt vmcnt(8)" ::: "memory");
        } else {
            asm volatile("s_waitcnt vmcnt(0)" ::: "memory");
        }
        __builtin_amdgcn_s_barrier();        // tile t landed for all waves
        __builtin_amdgcn_sched_barrier(0);   // no ds_read hoists above
        const bf16* la = &lda[cur * TILE_ELEMS];
        const bf16* lb = &ldb[cur * TILE_ELEMS];
#pragma unroll
        for (int ks = 0; ks < 2; ++ks) {
            bf16x8 af[4], bfr[4];
            int ca = (((ks * 4 + quad) ^ (col & 7)) * 8);  // swizzled chunk
#pragma unroll
            for (int t = 0; t < 4; ++t) {
                af[t]  = *(const bf16x8*)&la[(wr * 64 + t * 16 + col) * 64 + ca];
                bfr[t] = *(const bf16x8*)&lb[(wc * 64 + t * 16 + col) * 64 + ca];
            }
#pragma unroll
            for (int mr = 0; mr < 4; ++mr)
#pragma unroll
                for (int nc = 0; nc < 4; ++nc)
                    acc[mr][nc] = __builtin_amdgcn_mfma_f32_16x16x32_bf16(
                        af[mr], bfr[nc], acc[mr][nc], 0, 0, 0);
        }
        __builtin_amdgcn_sched_barrier(0);   // reads stay above the barrier
        __builtin_amdgcn_s_barrier();        // reads done before overwrite
        cur = nxt;
    }

#pragma unroll
    for (int nc = 0; nc < 4; ++nc) {
        int n = n0 + wc * 64 + nc * 16 + col;
        float bv = bias[n];
#pragma unroll
        for (int mr = 0; mr < 4; ++mr) {
#pragma unroll
            for (int r = 0; r < 4; ++r) {
                int row = m0 + wr * 64 + mr * 16 + quad * 4 + r;
                Cmat[(size_t)row * N + n] = (bf16)(acc[mr][nc][r] + bv);
            }
        }
    }
    if (n0 >= 2 * C_) {
        int batch = m0 >> 11;
        bf16* Vtb = Vt + (size_t)batch * C_ * T_;
        int t0 = (m0 & 2047) + wr * 64;
#pragma unroll
        for (int nc = 0; nc < 4; ++nc) {
            int n  = n0 + wc * 64 + nc * 16 + col;
            int vc = n - 2 * C_;
            float bv = bias[n];
#pragma unroll
            for (int mr = 0; mr < 4; ++mr) {
                int t  = t0 + mr * 16 + quad * 4;
                int tb = t & ~63;                 // 64-tile base
                int a  = (t >> 2) & 15;           // 4-chunk index in tile
                int ts = tb + ((a & 7) << 3) + ((a >> 3) << 2);  // permuted base
                bf16x4 pk = {(bf16)(acc[mr][nc][0] + bv), (bf16)(acc[mr][nc][1] + bv),
                             (bf16)(acc[mr][nc][2] + bv), (bf16)(acc[mr][nc][3] + bv)};
                *(bf16x4*)&Vtb[(size_t)vc * T_ + ts] = pk;
            }
        }
    }
}

// ---------------------------------------------------------------------------
// GEMM2: out[M][768](fp32) = yb[M][768](bf16) @ Bt^T + b.  Same T4+T2 loop.
// ---------------------------------------------------------------------------
__global__ __launch_bounds__(256) void gemm_proj(const bf16* __restrict__ A,
                                                 const bf16* __restrict__ Bt,
                                                 const float* __restrict__ bias,
                                                 float* __restrict__ Cmat,
                                                 int M, int N, int K) {
    __shared__ bf16 lda[2 * TILE_ELEMS];
    __shared__ bf16 ldb[2 * TILE_ELEMS];
    int tid  = threadIdx.x;
    int w    = tid >> 6;
    int lane = tid & 63;
    int col  = lane & 15, quad = lane >> 4;
    int wr   = w >> 1, wc = w & 1;
    int m0   = blockIdx.y * 128, n0 = blockIdx.x * 128;

    int srow = lane >> 3;
    int scol = ((lane & 7) ^ srow) * 8;
    const bf16* gA[4]; const bf16* gB[4]; bf16* lA[4]; bf16* lB[4];
#pragma unroll
    for (int i = 0; i < 4; ++i) {
        int seg = w * 4 + i;
        int row = seg * 8 + srow;
        gA[i] = &A[(size_t)(m0 + row) * K + scol];
        gB[i] = &Bt[(size_t)(n0 + row) * K + scol];
        lA[i] = &lda[seg * 512];
        lB[i] = &ldb[seg * 512];
    }

    const f32x4 zero = {0.f, 0.f, 0.f, 0.f};
    f32x4 acc[4][4];
#pragma unroll
    for (int mr = 0; mr < 4; ++mr)
#pragma unroll
        for (int nc = 0; nc < 4; ++nc) acc[mr][nc] = zero;

#pragma unroll
    for (int i = 0; i < 4; ++i) {
        gload_lds16(gA[i], lA[i]);
        gload_lds16(gB[i], lB[i]);
    }

    int cur = 0;
    for (int k0 = 0; k0 < K; k0 += 64) {
        int nxt = cur ^ 1;
        if (k0 + 64 < K) {
#pragma unroll
            for (int i = 0; i < 4; ++i) {
                gload_lds16(gA[i] + k0 + 64, lA[i] + nxt * TILE_ELEMS);
                gload_lds16(gB[i] + k0 + 64, lB[i] + nxt * TILE_ELEMS);
            }
            asm volatile("s_waitcnt vmcnt(8)" ::: "memory");
        } else {
            asm volatile("s_waitcnt vmcnt(0)" ::: "memory");
        }
        __builtin_amdgcn_s_barrier();
        __builtin_amdgcn_sched_barrier(0);
        const bf16* la = &lda[cur * TILE_ELEMS];
        const bf16* lb = &ldb[cur * TILE_ELEMS];
#pragma unroll
        for (int ks = 0; ks < 2; ++ks) {
            bf16x8 af[4], bfr[4];
            int ca = (((ks * 4 + quad) ^ (col & 7)) * 8);
#pragma unroll
            for (int t = 0; t < 4; ++t) {
                af[t]  = *(const bf16x8*)&la[(wr * 64 + t * 16 + col) * 64 + ca];
                bfr[t] = *(const bf16x8*)&lb[(wc * 64 + t * 16 + col) * 64 + ca];
            }
#pragma unroll
            for (int mr = 0; mr < 4; ++mr)
#pragma unroll
                for (int nc = 0; nc < 4; ++nc)
                    acc[mr][nc] = __builtin_amdgcn_mfma_f32_16x16x32_bf16(
                        af[mr], bfr[nc], acc[mr][nc], 0, 0, 0);
        }
        __builtin_amdgcn_sched_barrier(0);
        __builtin_amdgcn_s_barrier();
        cur = nxt;
    }

#pragma unroll
    for (int nc = 0; nc < 4; ++nc) {
        int n = n0 + wc * 64 + nc * 16 + col;
        float bv = bias[n];
#pragma unroll
        for (int mr = 0; mr < 4; ++mr) {
#pragma unroll
            for (int r = 0; r < 4; ++r) {
                int row = m0 + wr * 64 + mr * 16 + quad * 4 + r;
                Cmat[(size_t)row * N + n] = acc[mr][nc][r] + bv;
            }
        }
    }
}

// ---------------------------------------------------------------------------
// Fused causal flash attention — unchanged from r9 (58.5us-class structure:
// 1024 blocks 4/CU, T14 prefetch, P-in-register permuted-k PV, k-permuted V
// store, f32x4 lsum chains, heavy-first, T5 setprio around MFMA clusters).
// ---------------------------------------------------------------------------
__global__ __launch_bounds__(256) void attn_kernel(const bf16* __restrict__ qkv,
                                                   const bf16* __restrict__ Vt,
                                                   bf16* __restrict__ y,
                                                   int nGroups) {
    __shared__ bf16 ldsK[64 * KSTR];
    __shared__ bf16 ldsV[96 * VSTR];
    const int bid  = blockIdx.x;
    const int qt   = 31 - bid / nGroups;      // heavy blocks first
    const int g    = bid % nGroups;
    const int h    = g & 7, b = g >> 3;
    const int tid  = threadIdx.x;
    const int w    = tid >> 6, lane = tid & 63;
    const int col  = lane & 15, quad = lane >> 4;
    const float SCALE2 = 0.10206207261596577f * 1.4426950408889634f; // scale*log2e
    const float M0 = 24.0f;                    // static exponent shift (exact)
    const f32x4 zero = {0.f, 0.f, 0.f, 0.f};

    const bf16* qkvb = qkv + (size_t)b * T_ * QKN_;
    const bf16* Vtbh = Vt + (size_t)(b * H_ + h) * HS_ * T_;
    bf16* yb  = y + (size_t)b * T_ * C_;

    const int rbase = qt * 64 + w * 16;

    bf16x8 qf[3];
#pragma unroll
    for (int c = 0; c < 3; ++c)
        qf[c] = *(const bf16x8*)&qkvb[(size_t)(rbase + col) * QKN_ + h * HS_ + c * 32 + quad * 8];

    const bf16* pK[3]; const bf16* pV[3];
    bf16 *dK[3], *dV[3];
#pragma unroll
    for (int i = 0; i < 3; ++i) {
        int chunk = i * 256 + tid;
        int rK = chunk / 12, cK = chunk - rK * 12;
        pK[i] = qkvb + (size_t)rK * QKN_ + C_ + h * HS_ + cK * 8;
        dK[i] = &ldsK[rK * KSTR + cK * 8];
        int rV = chunk >> 3, cV = chunk & 7;
        pV[i] = Vtbh + (size_t)rV * T_ + cV * 8;
        dV[i] = &ldsV[rV * VSTR + cV * 8];
    }

    f32x4 o[6];
#pragma unroll
    for (int n2 = 0; n2 < 6; ++n2) o[n2] = zero;
    f32x4 lsum4 = zero;

    // prologue: prefetch jt=0 K/V into registers
    bf16x8 kreg[3], vreg[3];
#pragma unroll
    for (int i = 0; i < 3; ++i) {
        kreg[i] = *(const bf16x8*)pK[i];
        vreg[i] = *(const bf16x8*)pV[i];
        pK[i] += (size_t)64 * QKN_;
        pV[i] += 64;
    }

    const int njt = qt + 1;
    for (int jt = 0; jt < njt; ++jt) {
        int jb = jt * 64;
        __syncthreads();
        // write-late: regs -> LDS
#pragma unroll
        for (int i = 0; i < 3; ++i) {
            *(bf16x8*)dK[i] = kreg[i];
            *(bf16x8*)dV[i] = vreg[i];
        }
        __syncthreads();
        // issue-early: next tile's global loads fly under compute below
        if (jt + 1 < njt) {
#pragma unroll
            for (int i = 0; i < 3; ++i) {
                kreg[i] = *(const bf16x8*)pK[i];
                vreg[i] = *(const bf16x8*)pV[i];
                pK[i] += (size_t)64 * QKN_;
                pV[i] += 64;
            }
        }

        // QK^T: kf loaded per-nb (short live-range); T5 boost for MFMA cluster
        f32x4 st[4];
        __builtin_amdgcn_s_setprio(1);
#pragma unroll
        for (int nb = 0; nb < 4; ++nb) {
            st[nb] = zero;
#pragma unroll
            for (int c = 0; c < 3; ++c) {
                bf16x8 kf = *(const bf16x8*)&ldsK[(nb * 16 + col) * KSTR + c * 32 + quad * 8];
                st[nb] = __builtin_amdgcn_mfma_f32_16x16x32_bf16(
                    kf, qf[c], st[nb], 0, 0, 0);
            }
        }
        __builtin_amdgcn_s_setprio(0);

        if (jt == njt - 1) {
#pragma unroll
            for (int nb = 0; nb < 4; ++nb)
#pragma unroll
                for (int r = 0; r < 4; ++r) {
                    int jg = jb + nb * 16 + quad * 4 + r;
                    st[nb][r] = (jg <= rbase + col) ? fmaf(st[nb][r], SCALE2, -M0)
                                                    : NEG_BIG;
                }
        } else {
#pragma unroll
            for (int nb = 0; nb < 4; ++nb)
#pragma unroll
                for (int r = 0; r < 4; ++r)
                    st[nb][r] = fmaf(st[nb][r], SCALE2, -M0);
        }

#pragma unroll
        for (int nb = 0; nb < 4; ++nb) {
#pragma unroll
            for (int r = 0; r < 4; ++r)
                st[nb][r] = exp2f(st[nb][r]);
            lsum4 += st[nb];              // 4 independent FP chains
        }

        // Pack P as permuted-k B-operands (st stays in registers):
        // palo slot quad*8+j <-> k = (j<4?0:2)*16 + quad*4 + (j&3)
        // pahi slot quad*8+j <-> k = (j<4?1:3)*16 + quad*4 + (j&3)
        bf16x8 palo, pahi;
#pragma unroll
        for (int r = 0; r < 4; ++r) {
            palo[r]     = (bf16)st[0][r];
            palo[4 + r] = (bf16)st[2][r];
            pahi[r]     = (bf16)st[1][r];
            pahi[4 + r] = (bf16)st[3][r];
        }

        // V is k-permuted in storage: matching operand = contiguous b128
        __builtin_amdgcn_s_setprio(1);
#pragma unroll
        for (int n2 = 0; n2 < 6; ++n2) {
            const bf16* vrow = &ldsV[(n2 * 16 + col) * VSTR];
            bf16x8 vlo = *(const bf16x8*)&vrow[quad * 8];
            bf16x8 vhi = *(const bf16x8*)&vrow[32 + quad * 8];
            o[n2] = __builtin_amdgcn_mfma_f32_16x16x32_bf16(vlo, palo, o[n2], 0, 0, 0);
            o[n2] = __builtin_amdgcn_mfma_f32_16x16x32_bf16(vhi, pahi, o[n2], 0, 0, 0);
        }
        __builtin_amdgcn_s_setprio(0);
    }

    float lsum = (lsum4[0] + lsum4[1]) + (lsum4[2] + lsum4[3]);
    lsum += __shfl_xor(lsum, 16, 64);
    lsum += __shfl_xor(lsum, 32, 64);
    float linv = 1.0f / lsum;
#pragma unroll
    for (int n2 = 0; n2 < 6; ++n2) {
        bf16x4 pk = {(bf16)(o[n2][0] * linv), (bf16)(o[n2][1] * linv),
                     (bf16)(o[n2][2] * linv), (bf16)(o[n2][3] * linv)};
        *(bf16x4*)&yb[(size_t)(rbase + col) * C_ + h * HS_ + n2 * 16 + quad * 4] = pk;
    }
}

// ---------------------------------------------------------------------------
extern "C" void kernel_launch(void* const* d_in, const int* in_sizes, int n_in,
                              void* d_out, int out_size, void* d_ws, size_t ws_size,
                              hipStream_t stream) {
    (void)in_sizes; (void)n_in;
    const float* x      = (const float*)d_in[0];
    const float* W_attn = (const float*)d_in[1];
    const float* b_attn = (const float*)d_in[2];
    const float* W_proj = (const float*)d_in[3];
    const float* b_proj = (const float*)d_in[4];
    float* out = (float*)d_out;

    size_t e_wta = (size_t)QKN_ * C_;
    size_t e_wtp = (size_t)C_ * C_;
    size_t a_qkv = e_wta + e_wtp;
    size_t a_vt  = a_qkv + (size_t)M_ * QKN_;
    size_t a_yb  = a_vt + (size_t)M_ * C_;
    size_t needA = (a_yb + (size_t)M_ * C_) * sizeof(bf16);   // 67.6 MB
    size_t b_qkv = e_wta + e_wtp;
    size_t b_vt  = b_qkv + (size_t)T_ * QKN_;
    size_t b_yb  = b_vt + (size_t)T_ * C_;
    size_t needB = (b_yb + (size_t)T_ * C_) * sizeof(bf16);   // 20.4 MB

    if (ws_size >= needA) {
        bf16* Wt_attn = (bf16*)d_ws;
        bf16* Wt_proj = (bf16*)d_ws + e_wta;
        bf16* qkv     = (bf16*)d_ws + a_qkv;
        bf16* Vt      = (bf16*)d_ws + a_vt;
        bf16* yb      = (bf16*)d_ws + a_yb;
        bf16* xb      = yb;  // alias (xb dead before attn writes yb)
        prep_kernel<<<dim3(CONV_BLKS + TA_BLKS + TP_BLKS), 256, 0, stream>>>(
            x, xb, W_attn, Wt_attn, W_proj, Wt_proj);
        gemm_qkv<<<dim3(QKN_ / 128, M_ / 128), 256, 0, stream>>>(
            xb, Wt_attn, b_attn, qkv, Vt, M_, QKN_, C_);
        attn_kernel<<<dim3(32 * H_ * B_), 256, 0, stream>>>(qkv, Vt, yb, H_ * B_);
        gemm_proj<<<dim3(C_ / 128, M_ / 128), 256, 0, stream>>>(
            yb, Wt_proj, b_proj, out, M_, C_, C_);
    } else if (ws_size >= needB) {
        bf16* Wt_attn = (bf16*)d_ws;
        bf16* Wt_proj = (bf16*)d_ws + e_wta;
        bf16* qkv     = (bf16*)d_ws + b_qkv;
        bf16* Vt      = (bf16*)d_ws + b_vt;
        bf16* yb      = (bf16*)d_ws + b_yb;
        bf16* xb      = yb;  // alias per-batch
        transpose_kernel<<<dim3(QKN_ / 32, C_ / 32), dim3(32, 8), 0, stream>>>(W_attn, Wt_attn, C_, QKN_);
        transpose_kernel<<<dim3(C_ / 32, C_ / 32), dim3(32, 8), 0, stream>>>(W_proj, Wt_proj, C_, C_);
        for (int b = 0; b < B_; ++b) {
            const float* xf = x + (size_t)b * T_ * C_;
            float* outb     = out + (size_t)b * T_ * C_;
            convert_bf16_kernel<<<dim3(T_ * C_ / 8 / 256), 256, 0, stream>>>(xf, xb, T_ * C_ / 8);
            gemm_qkv<<<dim3(QKN_ / 128, T_ / 128), 256, 0, stream>>>(
                xb, Wt_attn, b_attn, qkv, Vt, T_, QKN_, C_);
            attn_kernel<<<dim3(32 * H_), 256, 0, stream>>>(qkv, Vt, yb, H_);
            gemm_proj<<<dim3(C_ / 128, T_ / 128), 256, 0, stream>>>(
                yb, Wt_proj, b_proj, outb, T_, C_, C_);
        }
    } else {
        sentinel_kernel<<<(out_size + 255) / 256, 256, 0, stream>>>(out, out_size);
    }
}